// Round 4
// baseline (175.665 us; speedup 1.0000x reference)
//
#include <hip/hip_runtime.h>
#include <stdint.h>

// B=2 S=2048 E=1024 H=16 DH=64.  M = B*S = 4096.
// ws layout (ushort elems): values 4M | qkin 4M | wqkv 3M | wout 1M | q 4M | k 4M | v 4M | attn 4M

typedef __attribute__((ext_vector_type(8))) short bf16x8;
typedef __attribute__((ext_vector_type(4))) short bf16x4;
typedef __attribute__((ext_vector_type(4))) float f32x4;
typedef __attribute__((ext_vector_type(4))) unsigned short u16x4;

#define DEV __device__ __forceinline__

DEV unsigned short f2bf(float f) {
  uint32_t u = __float_as_uint(f);
  u += 0x7fff + ((u >> 16) & 1);
  return (unsigned short)(u >> 16);
}

DEV float fast_exp2(float x) {
#if __has_builtin(__builtin_amdgcn_exp2f)
  return __builtin_amdgcn_exp2f(x);
#else
  return exp2f(x);
#endif
}

DEV f32x4 mfma16x16x16_bf16(bf16x4 a, bf16x4 b, f32x4 c) {
#if __has_builtin(__builtin_amdgcn_mfma_f32_16x16x16bf16_1k)
  return __builtin_amdgcn_mfma_f32_16x16x16bf16_1k(a, b, c, 0, 0, 0);
#else
  asm("v_mfma_f32_16x16x16_bf16 %0, %1, %2, %0" : "+v"(c) : "v"(a), "v"(b));
  return c;
#endif
}

DEV void gload_lds16(const void* g, void* l) {
  __builtin_amdgcn_global_load_lds(
      (const __attribute__((address_space(1))) uint32_t*)g,
      (__attribute__((address_space(3))) uint32_t*)l, 16, 0, 0);
}

// ---------------- weight convert f32 -> bf16 ----------------
__global__ __launch_bounds__(256) void wconv(const float* w1, const float* w2,
                                             unsigned short* o1, unsigned short* o2) {
  int i = blockIdx.x * 256 + threadIdx.x;  // over f32x4 chunks
  const int n1 = 3145728 / 4;              // in_proj_w chunks
  f32x4 v;
  if (i < n1) v = ((const f32x4*)w1)[i];
  else        v = ((const f32x4*)w2)[i - n1];
  u16x4 r;
#pragma unroll
  for (int j = 0; j < 4; ++j) r[j] = f2bf(v[j]);
  if (i < n1) ((u16x4*)o1)[i] = r;
  else        ((u16x4*)o2)[i - n1] = r;
}

// ---------------- LN + GELU + encodings ----------------
__global__ __launch_bounds__(256) void preproc(const float* x, const float* mul, const float* add,
                                               const float* lw, const float* lb,
                                               unsigned short* values, unsigned short* qkin) {
  int row = blockIdx.x;                 // 4096 rows
  size_t base = (size_t)row * 1024;
  int t = threadIdx.x;                  // 256 threads, 4 f32 each
  f32x4 v = ((const f32x4*)(x + base))[t];
  float s  = v[0] + v[1] + v[2] + v[3];
  float s2 = v[0]*v[0] + v[1]*v[1] + v[2]*v[2] + v[3]*v[3];
#pragma unroll
  for (int off = 1; off < 64; off <<= 1) {
    s  += __shfl_xor(s, off);
    s2 += __shfl_xor(s2, off);
  }
  __shared__ float rs[4], rs2[4];
  if ((t & 63) == 0) { rs[t >> 6] = s; rs2[t >> 6] = s2; }
  __syncthreads();
  s  = rs[0] + rs[1] + rs[2] + rs[3];
  s2 = rs2[0] + rs2[1] + rs2[2] + rs2[3];
  float mean = s * 0.0009765625f;
  float var  = s2 * 0.0009765625f - mean * mean;
  float rstd = rsqrtf(var + 1e-5f);
  f32x4 mu = ((const f32x4*)(mul + base))[t];
  f32x4 ad = ((const f32x4*)(add + base))[t];
  f32x4 w4 = ((const f32x4*)lw)[t];
  f32x4 b4 = ((const f32x4*)lb)[t];
  u16x4 vo, qo;
#pragma unroll
  for (int i = 0; i < 4; ++i) {
    float d = (v[i] - mean) * rstd * w4[i] + b4[i];
    float g = 0.5f * d * (1.0f + erff(d * 0.70710678118f));  // exact gelu
    vo[i] = f2bf(g);
    qo[i] = f2bf(g * mu[i] + ad[i]);
  }
  ((u16x4*)(values + base))[t] = vo;
  ((u16x4*)(qkin   + base))[t] = qo;
}

// ---------------- shared GEMM mainloop (C = A @ W^T), 128x128 tile, BK=64 ----------------
// LDS layout swizzle: elem (r,c) at byte r*128 + ((c*2) ^ ((r&7)<<4))
DEV void gemm_tile(const unsigned short* A, const unsigned short* B, int K,
                   int m0, int n0, unsigned short* ldsA, unsigned short* ldsB,
                   f32x4 acc[4][4]) {
  int t = threadIdx.x;
  int lane = t & 63;
  int w = t >> 6;
  int wr = w >> 1, wc = w & 1;
  int l15 = lane & 15, l4 = lane >> 4;
  for (int k0 = 0; k0 < K; k0 += 64) {
#pragma unroll
    for (int i = 0; i < 4; ++i) {
      int idx = i * 256 + t;                 // 16B chunk index 0..1023
      int r = idx >> 3;                      // row 0..127
      int slot = (idx & 7) ^ (r & 7);        // pre-swizzled source slot
      gload_lds16(A + (size_t)(m0 + r) * K + k0 + slot * 8,
                  (char*)ldsA + i * 4096 + w * 1024);
      gload_lds16(B + (size_t)(n0 + r) * K + k0 + slot * 8,
                  (char*)ldsB + i * 4096 + w * 1024);
    }
    __syncthreads();
#pragma unroll
    for (int kk = 0; kk < 2; ++kk) {
      bf16x8 af[4], bfr[4];
      int kb = kk * 64 + l4 * 16;
#pragma unroll
      for (int mm = 0; mm < 4; ++mm) {
        int r = wr * 64 + mm * 16 + l15;
        af[mm] = *(const bf16x8*)((const char*)ldsA + r * 128 + (kb ^ ((r & 7) << 4)));
      }
#pragma unroll
      for (int nn = 0; nn < 4; ++nn) {
        int r = wc * 64 + nn * 16 + l15;
        bfr[nn] = *(const bf16x8*)((const char*)ldsB + r * 128 + (kb ^ ((r & 7) << 4)));
      }
#pragma unroll
      for (int mm = 0; mm < 4; ++mm)
#pragma unroll
        for (int nn = 0; nn < 4; ++nn)
          acc[mm][nn] = __builtin_amdgcn_mfma_f32_16x16x32_bf16(af[mm], bfr[nn], acc[mm][nn], 0, 0, 0);
    }
    __syncthreads();
  }
}

// ---------------- QKV projection GEMM ----------------
// Q is pre-scaled by 1/sqrt(DH) * log2(e) so attention works in exp2 domain.
#define QSCALE 0.18033688011112042f

__global__ __launch_bounds__(256) void gemm_qkv(const unsigned short* Aqk, const unsigned short* Av,
                                                const unsigned short* W, const float* bias,
                                                unsigned short* qws, unsigned short* kws,
                                                unsigned short* vws) {
  __shared__ unsigned short ldsA[128 * 64];
  __shared__ unsigned short ldsB[128 * 64];
  int n0 = blockIdx.x * 128;   // 0..3071
  int m0 = blockIdx.y * 128;   // 0..4095
  const unsigned short* A = (n0 < 2048) ? Aqk : Av;
  f32x4 z = {0.f, 0.f, 0.f, 0.f};
  f32x4 acc[4][4];
#pragma unroll
  for (int mm = 0; mm < 4; ++mm)
#pragma unroll
    for (int nn = 0; nn < 4; ++nn) acc[mm][nn] = z;
  gemm_tile(A, W, 1024, m0, n0, ldsA, ldsB, acc);

  int t = threadIdx.x, lane = t & 63, w = t >> 6;
  int wr = w >> 1, wc = w & 1;
  int l15 = lane & 15, l4 = lane >> 4;
#pragma unroll
  for (int mm = 0; mm < 4; ++mm) {
    int row0 = m0 + wr * 64 + mm * 16 + l4 * 4;
#pragma unroll
    for (int nn = 0; nn < 4; ++nn) {
      int col = n0 + wc * 64 + nn * 16 + l15;
      float bs = bias[col];
      int region = col >> 10;
      int e = col & 1023;
      unsigned short* dst = region == 0 ? qws : (region == 1 ? kws : vws);
      float scl = region == 0 ? QSCALE : 1.0f;
      int h = e >> 6, d = e & 63;
#pragma unroll
      for (int reg = 0; reg < 4; ++reg) {
        int r = row0 + reg;
        int bb = r >> 11, s = r & 2047;
        dst[(((size_t)(bb * 16 + h)) * 2048 + s) * 64 + d] = f2bf((acc[mm][nn][reg] + bs) * scl);
      }
    }
  }
}

// ---------------- flash attention: 8 waves, split-KV (2 groups x 4 waves), 32 q/wave ----------------
DEV void stage_k(const unsigned short* Kp, int kv0, unsigned short* buf, int tg) {
  int wl = tg >> 6;   // wave within group 0..3
#pragma unroll
  for (int i = 0; i < 2; ++i) {
    int idx = i * 256 + tg;
    int r = idx >> 3;
    int slot = (idx & 7) ^ (r & 7);
    gload_lds16(Kp + (size_t)(kv0 + r) * 64 + slot * 8,
                (char*)buf + i * 4096 + wl * 1024);
  }
}

DEV void write_vt(unsigned short* vtbuf, int kvp, int d0, bf16x8 v0, bf16x8 v1) {
#pragma unroll
  for (int i = 0; i < 8; ++i) {
    int dd = d0 + i;
    uint32_t pk = (uint32_t)(unsigned short)v0[i] | ((uint32_t)(unsigned short)v1[i] << 16);
    *(uint32_t*)((char*)vtbuf + dd * 128 + ((4 * kvp) ^ ((dd & 7) << 4))) = pk;
  }
}

__global__ __launch_bounds__(512) void attn_kernel(const unsigned short* qws, const unsigned short* kws,
                                                   const unsigned short* vws, unsigned short* attnb) {
  int bh = blockIdx.y;            // 32
  int q0 = blockIdx.x * 128;      // q tile per block (32 per wave)
  int t = threadIdx.x;
  int lane = t & 63, w = t >> 6;  // w: 0..7
  int g = w >> 2;                 // kv half
  int wg = w & 3;                 // wave within group
  int tg = t & 255;               // thread within group
  int l15 = lane & 15, l4 = lane >> 4;
  __shared__ unsigned short ldsK[2][2][64 * 64];   // [group][buf]
  __shared__ unsigned short ldsVT[2][2][64 * 64];

  const unsigned short* Qp = qws + ((size_t)bh * 2048 + q0 + wg * 32) * 64;
  const unsigned short* Kp = kws + ((size_t)bh * 2048 + g * 1024) * 64;
  const unsigned short* Vp = vws + ((size_t)bh * 2048 + g * 1024) * 64;

  // Q fragments (B-operand of swapped QK): lane holds Q[q = qs*16+l15][d = kk*32 + l4*8 .. +7]
  bf16x8 aq[2][2];
#pragma unroll
  for (int qs = 0; qs < 2; ++qs)
#pragma unroll
    for (int kk = 0; kk < 2; ++kk)
      aq[qs][kk] = *(const bf16x8*)(Qp + (qs * 16 + l15) * 64 + kk * 32 + l4 * 8);

  f32x4 z = {0.f, 0.f, 0.f, 0.f};
  f32x4 o[2][4];
#pragma unroll
  for (int qs = 0; qs < 2; ++qs)
#pragma unroll
    for (int i = 0; i < 4; ++i) o[qs][i] = z;
  float m_run[2] = {-1e30f, -1e30f};   // per lane: stats for q-row qs*16+l15 (replicated across l4)
  float l_run[2] = {0.f, 0.f};

  int kvp = tg & 31, d0 = ((tg >> 5) & 7) * 8;
  int osrc[4];
#pragma unroll
  for (int reg = 0; reg < 4; ++reg)
    osrc[reg] = (lane & 48) | (((lane >> 4) & 3) << 2) | reg;  // stats lane holding q-row l4*4+reg

  // ---- prologue: stage tile 0 of this group's KV half ----
  {
    bf16x8 v0 = *(const bf16x8*)(Vp + (size_t)(2 * kvp) * 64 + d0);
    bf16x8 v1 = *(const bf16x8*)(Vp + (size_t)(2 * kvp + 1) * 64 + d0);
    stage_k(Kp, 0, &ldsK[g][0][0], tg);
    write_vt(&ldsVT[g][0][0], kvp, d0, v0, v1);
  }
  __syncthreads();

  for (int it = 0; it < 16; ++it) {
    int cur = it & 1;
    bf16x8 nv0, nv1;
    if (it < 15) {
      int kvn = (it + 1) * 64;
      nv0 = *(const bf16x8*)(Vp + (size_t)(kvn + 2 * kvp) * 64 + d0);
      nv1 = *(const bf16x8*)(Vp + (size_t)(kvn + 2 * kvp + 1) * 64 + d0);
      stage_k(Kp, kvn, &ldsK[g][cur ^ 1][0], tg);
    }

    // S^T = K @ Q^T : per qs, C col = q (l15), row = kv = nn*16 + l4*4 + reg
    f32x4 sc[2][4];
#pragma unroll
    for (int qs = 0; qs < 2; ++qs)
#pragma unroll
      for (int nn = 0; nn < 4; ++nn) sc[qs][nn] = z;
    __builtin_amdgcn_s_setprio(1);
#pragma unroll
    for (int kk = 0; kk < 2; ++kk) {
#pragma unroll
      for (int nn = 0; nn < 4; ++nn) {
        int r = nn * 16 + l15;
        bf16x8 bk = *(const bf16x8*)((const char*)&ldsK[g][cur][0] + r * 128 + ((kk * 64 + l4 * 16) ^ ((r & 7) << 4)));
#pragma unroll
        for (int qs = 0; qs < 2; ++qs)
          sc[qs][nn] = __builtin_amdgcn_mfma_f32_16x16x32_bf16(bk, aq[qs][kk], sc[qs][nn], 0, 0, 0);
      }
    }
    __builtin_amdgcn_s_setprio(0);

    // online softmax per q-set
    bf16x4 pa[2][4];
    float pmax[2];
#pragma unroll
    for (int qs = 0; qs < 2; ++qs) {
      float mA = fmaxf(fmaxf(sc[qs][0][0], sc[qs][0][1]), fmaxf(sc[qs][0][2], sc[qs][0][3]));
      float mB = fmaxf(fmaxf(sc[qs][1][0], sc[qs][1][1]), fmaxf(sc[qs][1][2], sc[qs][1][3]));
      float mC = fmaxf(fmaxf(sc[qs][2][0], sc[qs][2][1]), fmaxf(sc[qs][2][2], sc[qs][2][3]));
      float mD = fmaxf(fmaxf(sc[qs][3][0], sc[qs][3][1]), fmaxf(sc[qs][3][2], sc[qs][3][3]));
      float pm = fmaxf(fmaxf(mA, mB), fmaxf(mC, mD));
      pm = fmaxf(pm, __shfl_xor(pm, 16));
      pm = fmaxf(pm, __shfl_xor(pm, 32));
      pmax[qs] = pm;
    }

    // deferred-max rescale (THR=8 in log2 domain), shared branch
    if (__any(fmaxf(pmax[0] - m_run[0], pmax[1] - m_run[1]) > 8.0f)) {
#pragma unroll
      for (int qs = 0; qs < 2; ++qs) {
        float mnew = fmaxf(m_run[qs], pmax[qs]);
        float fs = fast_exp2(m_run[qs] - mnew);
        m_run[qs] = mnew;
        l_run[qs] *= fs;
        float fo[4];
#pragma unroll
        for (int reg = 0; reg < 4; ++reg) fo[reg] = __shfl(fs, osrc[reg]);
#pragma unroll
        for (int dt = 0; dt < 4; ++dt)
#pragma unroll
          for (int reg = 0; reg < 4; ++reg) o[qs][dt][reg] *= fo[reg];
      }
    }

    // P = exp2(S - m); pack into 16x16x16 A-fragments (k = l4*4 + j)
#pragma unroll
    for (int qs = 0; qs < 2; ++qs) {
      float psum = 0.f;
#pragma unroll
      for (int nn = 0; nn < 4; ++nn) {
        float p0 = fast_exp2(sc[qs][nn][0] - m_run[qs]);
        float p1 = fast_exp2(sc[qs][nn][1] - m_run[qs]);
        float p2 = fast_exp2(sc[qs][nn][2] - m_run[qs]);
        float p3 = fast_exp2(sc[qs][nn][3] - m_run[qs]);
        psum += (p0 + p1) + (p2 + p3);
        pa[qs][nn][0] = (short)(__float_as_uint(p0) >> 16);
        pa[qs][nn][1] = (short)(__float_as_uint(p1) >> 16);
        pa[qs][nn][2] = (short)(__float_as_uint(p2) >> 16);
        pa[qs][nn][3] = (short)(__float_as_uint(p3) >> 16);
      }
      psum += __shfl_xor(psum, 16);
      psum += __shfl_xor(psum, 32);
      l_run[qs] += psum;
    }

    // O += P @ V  (16x16x16 MFMAs; B-frag = 4 contig kv of VT row d, shared across qs)
    __builtin_amdgcn_s_setprio(1);
#pragma unroll
    for (int dt = 0; dt < 4; ++dt) {
      int r = dt * 16 + l15;
#pragma unroll
      for (int nn = 0; nn < 4; ++nn) {
        bf16x4 vb = *(const bf16x4*)((const char*)&ldsVT[g][cur][0] + r * 128 + ((nn * 32 + l4 * 8) ^ ((r & 7) << 4)));
#pragma unroll
        for (int qs = 0; qs < 2; ++qs)
          o[qs][dt] = mfma16x16x16_bf16(pa[qs][nn], vb, o[qs][dt]);
      }
    }
    __builtin_amdgcn_s_setprio(0);

    if (it < 15) write_vt(&ldsVT[g][cur ^ 1][0], kvp, d0, nv0, nv1);
    __syncthreads();
  }

  // ---- merge the two KV-half partials via LDS (reuse ldsK/ldsVT) ----
  float* mo = (float*)&ldsK[0][0][0];    // 32 KB: [wg][qs][dt][reg][lane] f32
  float* ms = (float*)&ldsVT[0][0][0];   // stats: [wg][qs][{m,l}][lane] f32
  if (g == 1) {
#pragma unroll
    for (int qs = 0; qs < 2; ++qs) {
#pragma unroll
      for (int dt = 0; dt < 4; ++dt)
#pragma unroll
        for (int reg = 0; reg < 4; ++reg)
          mo[(((wg * 2 + qs) * 4 + dt) * 4 + reg) * 64 + lane] = o[qs][dt][reg];
      ms[((wg * 2 + qs) * 2 + 0) * 64 + lane] = m_run[qs];
      ms[((wg * 2 + qs) * 2 + 1) * 64 + lane] = l_run[qs];
    }
  }
  __syncthreads();
  if (g == 0) {
    int b = bh >> 4, h = bh & 15;
#pragma unroll
    for (int qs = 0; qs < 2; ++qs) {
      float m1 = ms[((wg * 2 + qs) * 2 + 0) * 64 + lane];
      float l1 = ms[((wg * 2 + qs) * 2 + 1) * 64 + lane];
      float m  = fmaxf(m_run[qs], m1);
      float f0 = fast_exp2(m_run[qs] - m);
      float f1 = fast_exp2(m1 - m);
      float linv = 1.0f / (l_run[qs] * f0 + l1 * f1);
      float a0 = f0 * linv, a1 = f1 * linv;
      float b0[4], b1[4];
#pragma unroll
      for (int reg = 0; reg < 4; ++reg) {
        b0[reg] = __shfl(a0, osrc[reg]);
        b1[reg] = __shfl(a1, osrc[reg]);
      }
#pragma unroll
      for (int reg = 0; reg < 4; ++reg) {
        int qg = q0 + wg * 32 + qs * 16 + l4 * 4 + reg;
#pragma unroll
        for (int dt = 0; dt < 4; ++dt) {
          int d = dt * 16 + l15;
          float o1v = mo[(((wg * 2 + qs) * 4 + dt) * 4 + reg) * 64 + lane];
          attnb[((size_t)b * 2048 + qg) * 1024 + h * 64 + d] =
              f2bf(o[qs][dt][reg] * b0[reg] + o1v * b1[reg]);
        }
      }
    }
  }
}

// ---------------- out projection + bias + residual ----------------
__global__ __launch_bounds__(256) void gemm_out(const unsigned short* A, const unsigned short* W,
                                                const float* bias, const float* resid, float* out) {
  __shared__ unsigned short ldsA[128 * 64];
  __shared__ unsigned short ldsB[128 * 64];
  int n0 = blockIdx.x * 128;   // 0..1023
  int m0 = blockIdx.y * 128;
  f32x4 z = {0.f, 0.f, 0.f, 0.f};
  f32x4 acc[4][4];
#pragma unroll
  for (int mm = 0; mm < 4; ++mm)
#pragma unroll
    for (int nn = 0; nn < 4; ++nn) acc[mm][nn] = z;
  gemm_tile(A, W, 1024, m0, n0, ldsA, ldsB, acc);

  int t = threadIdx.x, lane = t & 63, w = t >> 6;
  int wr = w >> 1, wc = w & 1;
  int l15 = lane & 15, l4 = lane >> 4;
#pragma unroll
  for (int mm = 0; mm < 4; ++mm) {
#pragma unroll
    for (int nn = 0; nn < 4; ++nn) {
      int col = n0 + wc * 64 + nn * 16 + l15;
      float bs = bias[col];
#pragma unroll
      for (int reg = 0; reg < 4; ++reg) {
        int r = m0 + wr * 64 + mm * 16 + l4 * 4 + reg;
        size_t off = (size_t)r * 1024 + col;
        out[off] = acc[mm][nn][reg] + bs + resid[off];
      }
    }
  }
}

extern "C" void kernel_launch(void* const* d_in, const int* in_sizes, int n_in,
                              void* d_out, int out_size, void* d_ws, size_t ws_size,
                              hipStream_t stream) {
  const float* in_feats   = (const float*)d_in[0];
  const float* mul_encs   = (const float*)d_in[1];
  const float* add_encs   = (const float*)d_in[2];
  const float* ln_w       = (const float*)d_in[3];
  const float* ln_b       = (const float*)d_in[4];
  const float* in_proj_w  = (const float*)d_in[5];
  const float* in_proj_b  = (const float*)d_in[6];
  const float* out_proj_w = (const float*)d_in[7];
  const float* out_proj_b = (const float*)d_in[8];
  float* out = (float*)d_out;

  unsigned short* ws = (unsigned short*)d_ws;
  unsigned short* values = ws;
  unsigned short* qkin   = values + 4194304;
  unsigned short* wqkv   = qkin + 4194304;
  unsigned short* wout   = wqkv + 3145728;
  unsigned short* qws    = wout + 1048576;
  unsigned short* kws    = qws + 4194304;
  unsigned short* vws    = kws + 4194304;
  unsigned short* attnb  = vws + 4194304;

  wconv<<<4096, 256, 0, stream>>>(in_proj_w, out_proj_w, wqkv, wout);
  preproc<<<4096, 256, 0, stream>>>(in_feats, mul_encs, add_encs, ln_w, ln_b, values, qkin);
  gemm_qkv<<<dim3(24, 32), 256, 0, stream>>>(qkin, values, wqkv, in_proj_b, qws, kws, vws);
  attn_kernel<<<dim3(16, 32), 512, 0, stream>>>(qws, kws, vws, attnb);
  gemm_out<<<dim3(8, 32), 256, 0, stream>>>(attnb, wout, out_proj_b, in_feats, out);
}

// Round 5
// 163.364 us; speedup vs baseline: 1.0753x; 1.0753x over previous
//
#include <hip/hip_runtime.h>
#include <stdint.h>

// B=2 S=2048 E=1024 H=16 DH=64.  M = B*S = 4096.
// ws layout (ushort elems): values 4M | qkin 4M | wqkv 3M | wout 1M | q 4M | k 4M | v 4M | attn 4M

typedef __attribute__((ext_vector_type(8))) short bf16x8;
typedef __attribute__((ext_vector_type(4))) short bf16x4;
typedef __attribute__((ext_vector_type(4))) float f32x4;
typedef __attribute__((ext_vector_type(4))) unsigned short u16x4;

#define DEV __device__ __forceinline__

DEV unsigned short f2bf(float f) {
  uint32_t u = __float_as_uint(f);
  u += 0x7fff + ((u >> 16) & 1);
  return (unsigned short)(u >> 16);
}

DEV float fast_exp2(float x) {
#if __has_builtin(__builtin_amdgcn_exp2f)
  return __builtin_amdgcn_exp2f(x);
#else
  return exp2f(x);
#endif
}

DEV f32x4 mfma16x16x16_bf16(bf16x4 a, bf16x4 b, f32x4 c) {
#if __has_builtin(__builtin_amdgcn_mfma_f32_16x16x16bf16_1k)
  return __builtin_amdgcn_mfma_f32_16x16x16bf16_1k(a, b, c, 0, 0, 0);
#else
  asm("v_mfma_f32_16x16x16_bf16 %0, %1, %2, %0" : "+v"(c) : "v"(a), "v"(b));
  return c;
#endif
}

DEV void gload_lds16(const void* g, void* l) {
  __builtin_amdgcn_global_load_lds(
      (const __attribute__((address_space(1))) uint32_t*)g,
      (__attribute__((address_space(3))) uint32_t*)l, 16, 0, 0);
}

#define WAIT_VM4()   asm volatile("s_waitcnt vmcnt(4)" ::: "memory")
#define WAIT_VM0()   asm volatile("s_waitcnt vmcnt(0)" ::: "memory")
#define WAIT_LGKM0() asm volatile("s_waitcnt lgkmcnt(0)" ::: "memory")
#define SBAR()       __builtin_amdgcn_sched_barrier(0)

// ---------------- weight convert f32 -> bf16 ----------------
__global__ __launch_bounds__(256) void wconv(const float* w1, const float* w2,
                                             unsigned short* o1, unsigned short* o2) {
  int i = blockIdx.x * 256 + threadIdx.x;  // over f32x4 chunks
  const int n1 = 3145728 / 4;              // in_proj_w chunks
  f32x4 v;
  if (i < n1) v = ((const f32x4*)w1)[i];
  else        v = ((const f32x4*)w2)[i - n1];
  u16x4 r;
#pragma unroll
  for (int j = 0; j < 4; ++j) r[j] = f2bf(v[j]);
  if (i < n1) ((u16x4*)o1)[i] = r;
  else        ((u16x4*)o2)[i - n1] = r;
}

// ---------------- LN + GELU + encodings ----------------
__global__ __launch_bounds__(256) void preproc(const float* x, const float* mul, const float* add,
                                               const float* lw, const float* lb,
                                               unsigned short* values, unsigned short* qkin) {
  int row = blockIdx.x;                 // 4096 rows
  size_t base = (size_t)row * 1024;
  int t = threadIdx.x;                  // 256 threads, 4 f32 each
  f32x4 v = ((const f32x4*)(x + base))[t];
  float s  = v[0] + v[1] + v[2] + v[3];
  float s2 = v[0]*v[0] + v[1]*v[1] + v[2]*v[2] + v[3]*v[3];
#pragma unroll
  for (int off = 1; off < 64; off <<= 1) {
    s  += __shfl_xor(s, off);
    s2 += __shfl_xor(s2, off);
  }
  __shared__ float rs[4], rs2[4];
  if ((t & 63) == 0) { rs[t >> 6] = s; rs2[t >> 6] = s2; }
  __syncthreads();
  s  = rs[0] + rs[1] + rs[2] + rs[3];
  s2 = rs2[0] + rs2[1] + rs2[2] + rs2[3];
  float mean = s * 0.0009765625f;
  float var  = s2 * 0.0009765625f - mean * mean;
  float rstd = rsqrtf(var + 1e-5f);
  f32x4 mu = ((const f32x4*)(mul + base))[t];
  f32x4 ad = ((const f32x4*)(add + base))[t];
  f32x4 w4 = ((const f32x4*)lw)[t];
  f32x4 b4 = ((const f32x4*)lb)[t];
  u16x4 vo, qo;
#pragma unroll
  for (int i = 0; i < 4; ++i) {
    float d = (v[i] - mean) * rstd * w4[i] + b4[i];
    float g = 0.5f * d * (1.0f + erff(d * 0.70710678118f));  // exact gelu
    vo[i] = f2bf(g);
    qo[i] = f2bf(g * mu[i] + ad[i]);
  }
  ((u16x4*)(values + base))[t] = vo;
  ((u16x4*)(qkin   + base))[t] = qo;
}

// ---------------- shared GEMM mainloop (C = A @ W^T), 128x128 tile, BK=64 ----------------
// LDS layout swizzle: elem (r,c) at byte r*128 + ((c*2) ^ ((r&7)<<4))
DEV void gemm_tile(const unsigned short* A, const unsigned short* B, int K,
                   int m0, int n0, unsigned short* ldsA, unsigned short* ldsB,
                   f32x4 acc[4][4]) {
  int t = threadIdx.x;
  int lane = t & 63;
  int w = t >> 6;
  int wr = w >> 1, wc = w & 1;
  int l15 = lane & 15, l4 = lane >> 4;
  for (int k0 = 0; k0 < K; k0 += 64) {
#pragma unroll
    for (int i = 0; i < 4; ++i) {
      int idx = i * 256 + t;                 // 16B chunk index 0..1023
      int r = idx >> 3;                      // row 0..127
      int slot = (idx & 7) ^ (r & 7);        // pre-swizzled source slot
      gload_lds16(A + (size_t)(m0 + r) * K + k0 + slot * 8,
                  (char*)ldsA + i * 4096 + w * 1024);
      gload_lds16(B + (size_t)(n0 + r) * K + k0 + slot * 8,
                  (char*)ldsB + i * 4096 + w * 1024);
    }
    __syncthreads();
#pragma unroll
    for (int kk = 0; kk < 2; ++kk) {
      bf16x8 af[4], bfr[4];
      int kb = kk * 64 + l4 * 16;
#pragma unroll
      for (int mm = 0; mm < 4; ++mm) {
        int r = wr * 64 + mm * 16 + l15;
        af[mm] = *(const bf16x8*)((const char*)ldsA + r * 128 + (kb ^ ((r & 7) << 4)));
      }
#pragma unroll
      for (int nn = 0; nn < 4; ++nn) {
        int r = wc * 64 + nn * 16 + l15;
        bfr[nn] = *(const bf16x8*)((const char*)ldsB + r * 128 + (kb ^ ((r & 7) << 4)));
      }
#pragma unroll
      for (int mm = 0; mm < 4; ++mm)
#pragma unroll
        for (int nn = 0; nn < 4; ++nn)
          acc[mm][nn] = __builtin_amdgcn_mfma_f32_16x16x32_bf16(af[mm], bfr[nn], acc[mm][nn], 0, 0, 0);
    }
    __syncthreads();
  }
}

// ---------------- QKV projection GEMM ----------------
// Q is pre-scaled by 1/sqrt(DH) * log2(e) so attention works in exp2 domain.
#define QSCALE 0.18033688011112042f

__global__ __launch_bounds__(256) void gemm_qkv(const unsigned short* Aqk, const unsigned short* Av,
                                                const unsigned short* W, const float* bias,
                                                unsigned short* qws, unsigned short* kws,
                                                unsigned short* vws) {
  __shared__ unsigned short ldsA[128 * 64];
  __shared__ unsigned short ldsB[128 * 64];
  int n0 = blockIdx.x * 128;   // 0..3071
  int m0 = blockIdx.y * 128;   // 0..4095
  const unsigned short* A = (n0 < 2048) ? Aqk : Av;
  f32x4 z = {0.f, 0.f, 0.f, 0.f};
  f32x4 acc[4][4];
#pragma unroll
  for (int mm = 0; mm < 4; ++mm)
#pragma unroll
    for (int nn = 0; nn < 4; ++nn) acc[mm][nn] = z;
  gemm_tile(A, W, 1024, m0, n0, ldsA, ldsB, acc);

  int t = threadIdx.x, lane = t & 63, w = t >> 6;
  int wr = w >> 1, wc = w & 1;
  int l15 = lane & 15, l4 = lane >> 4;
#pragma unroll
  for (int mm = 0; mm < 4; ++mm) {
    int row0 = m0 + wr * 64 + mm * 16 + l4 * 4;
#pragma unroll
    for (int nn = 0; nn < 4; ++nn) {
      int col = n0 + wc * 64 + nn * 16 + l15;
      float bs = bias[col];
      int region = col >> 10;
      int e = col & 1023;
      unsigned short* dst = region == 0 ? qws : (region == 1 ? kws : vws);
      float scl = region == 0 ? QSCALE : 1.0f;
      int h = e >> 6, d = e & 63;
#pragma unroll
      for (int reg = 0; reg < 4; ++reg) {
        int r = row0 + reg;
        int bb = r >> 11, s = r & 2047;
        dst[(((size_t)(bb * 16 + h)) * 2048 + s) * 64 + d] = f2bf((acc[mm][nn][reg] + bs) * scl);
      }
    }
  }
}

// ---------------- flash attention: counted-vmcnt pipeline, 4 waves, 32 q/wave ----------------
DEV void stage_k(const unsigned short* Kp, int kv0, unsigned short* buf, int t) {
  int w = t >> 6;
#pragma unroll
  for (int i = 0; i < 2; ++i) {
    int idx = i * 256 + t;
    int r = idx >> 3;
    int slot = (idx & 7) ^ (r & 7);
    gload_lds16(Kp + (size_t)(kv0 + r) * 64 + slot * 8,
                (char*)buf + i * 4096 + w * 1024);
  }
}

DEV void write_vt(unsigned short* vtbuf, int kvp, int d0, bf16x8 v0, bf16x8 v1) {
#pragma unroll
  for (int i = 0; i < 8; ++i) {
    int dd = d0 + i;
    uint32_t pk = (uint32_t)(unsigned short)v0[i] | ((uint32_t)(unsigned short)v1[i] << 16);
    *(uint32_t*)((char*)vtbuf + dd * 128 + ((4 * kvp) ^ ((dd & 7) << 4))) = pk;
  }
}

DEV void attn_compute(const unsigned short* kbuf, const unsigned short* vtbuf,
                      const bf16x8 (&aq)[2][2], f32x4 (&o)[2][4],
                      float (&m_run)[2], float (&l_run)[2], const int (&osrc)[4],
                      int l15, int l4) {
  f32x4 z = {0.f, 0.f, 0.f, 0.f};
  f32x4 sc[2][4];
#pragma unroll
  for (int qs = 0; qs < 2; ++qs)
#pragma unroll
    for (int nn = 0; nn < 4; ++nn) sc[qs][nn] = z;
  __builtin_amdgcn_s_setprio(1);
#pragma unroll
  for (int kk = 0; kk < 2; ++kk) {
#pragma unroll
    for (int nn = 0; nn < 4; ++nn) {
      int r = nn * 16 + l15;
      bf16x8 bk = *(const bf16x8*)((const char*)kbuf + r * 128 + ((kk * 64 + l4 * 16) ^ ((r & 7) << 4)));
#pragma unroll
      for (int qs = 0; qs < 2; ++qs)
        sc[qs][nn] = __builtin_amdgcn_mfma_f32_16x16x32_bf16(bk, aq[qs][kk], sc[qs][nn], 0, 0, 0);
    }
  }
  __builtin_amdgcn_s_setprio(0);

  bf16x4 pa[2][4];
  float pmax[2];
#pragma unroll
  for (int qs = 0; qs < 2; ++qs) {
    float mA = fmaxf(fmaxf(sc[qs][0][0], sc[qs][0][1]), fmaxf(sc[qs][0][2], sc[qs][0][3]));
    float mB = fmaxf(fmaxf(sc[qs][1][0], sc[qs][1][1]), fmaxf(sc[qs][1][2], sc[qs][1][3]));
    float mC = fmaxf(fmaxf(sc[qs][2][0], sc[qs][2][1]), fmaxf(sc[qs][2][2], sc[qs][2][3]));
    float mD = fmaxf(fmaxf(sc[qs][3][0], sc[qs][3][1]), fmaxf(sc[qs][3][2], sc[qs][3][3]));
    float pm = fmaxf(fmaxf(mA, mB), fmaxf(mC, mD));
    pm = fmaxf(pm, __shfl_xor(pm, 16));
    pm = fmaxf(pm, __shfl_xor(pm, 32));
    pmax[qs] = pm;
  }

  if (__any(fmaxf(pmax[0] - m_run[0], pmax[1] - m_run[1]) > 8.0f)) {
#pragma unroll
    for (int qs = 0; qs < 2; ++qs) {
      float mnew = fmaxf(m_run[qs], pmax[qs]);
      float fs = fast_exp2(m_run[qs] - mnew);
      m_run[qs] = mnew;
      l_run[qs] *= fs;
      float fo[4];
#pragma unroll
      for (int reg = 0; reg < 4; ++reg) fo[reg] = __shfl(fs, osrc[reg]);
#pragma unroll
      for (int dt = 0; dt < 4; ++dt)
#pragma unroll
        for (int reg = 0; reg < 4; ++reg) o[qs][dt][reg] *= fo[reg];
    }
  }

#pragma unroll
  for (int qs = 0; qs < 2; ++qs) {
    float psum = 0.f;
#pragma unroll
    for (int nn = 0; nn < 4; ++nn) {
      float p0 = fast_exp2(sc[qs][nn][0] - m_run[qs]);
      float p1 = fast_exp2(sc[qs][nn][1] - m_run[qs]);
      float p2 = fast_exp2(sc[qs][nn][2] - m_run[qs]);
      float p3 = fast_exp2(sc[qs][nn][3] - m_run[qs]);
      psum += (p0 + p1) + (p2 + p3);
      pa[qs][nn][0] = (short)(__float_as_uint(p0) >> 16);
      pa[qs][nn][1] = (short)(__float_as_uint(p1) >> 16);
      pa[qs][nn][2] = (short)(__float_as_uint(p2) >> 16);
      pa[qs][nn][3] = (short)(__float_as_uint(p3) >> 16);
    }
    psum += __shfl_xor(psum, 16);
    psum += __shfl_xor(psum, 32);
    l_run[qs] += psum;
  }

  __builtin_amdgcn_s_setprio(1);
#pragma unroll
  for (int dt = 0; dt < 4; ++dt) {
    int r = dt * 16 + l15;
#pragma unroll
    for (int nn = 0; nn < 4; ++nn) {
      bf16x4 vb = *(const bf16x4*)((const char*)vtbuf + r * 128 + ((nn * 32 + l4 * 8) ^ ((r & 7) << 4)));
#pragma unroll
      for (int qs = 0; qs < 2; ++qs)
        o[qs][dt] = mfma16x16x16_bf16(pa[qs][nn], vb, o[qs][dt]);
    }
  }
  __builtin_amdgcn_s_setprio(0);
}

#define VLOADR(kv, r) (*(const bf16x8*)(Vp + (size_t)((kv) + 2 * kvp + (r)) * 64 + d0))

// One pipelined iteration. ph = it & 3 (compile-time), full: prefetch+vm4, last: no VT write/barrier.
#define AITER(ph, itc, full, last)                                                   \
  {                                                                                  \
    if (full) {                                                                      \
      int kvn = ((itc) + 2) * 64;                                                    \
      stage_k(Kp, kvn, &ldsK[((ph) + 2) & 3][0], t);                                 \
      if (((ph) & 1) == 0) { nvA0 = VLOADR(kvn, 0); nvA1 = VLOADR(kvn, 1); }         \
      else                 { nvB0 = VLOADR(kvn, 0); nvB1 = VLOADR(kvn, 1); }         \
    }                                                                                \
    SBAR();                                                                          \
    attn_compute(&ldsK[(ph) & 3][0], &ldsVT[(ph) & 1][0], aq, o, m_run, l_run,       \
                 osrc, l15, l4);                                                     \
    SBAR();                                                                          \
    if (full) { WAIT_VM4(); } else { WAIT_VM0(); }                                   \
    if (!(last)) {                                                                   \
      if (((ph) & 1) == 0) write_vt(&ldsVT[((ph) + 1) & 1][0], kvp, d0, nvB0, nvB1); \
      else                 write_vt(&ldsVT[((ph) + 1) & 1][0], kvp, d0, nvA0, nvA1); \
      WAIT_LGKM0();                                                                  \
      SBAR();                                                                        \
      __builtin_amdgcn_s_barrier();                                                  \
      SBAR();                                                                        \
    }                                                                                \
  }

__global__ __launch_bounds__(256) void attn_kernel(const unsigned short* qws, const unsigned short* kws,
                                                   const unsigned short* vws, unsigned short* attnb) {
  int bh = blockIdx.y;            // 32
  int q0 = blockIdx.x * 128;      // q tile per block (32 per wave)
  int t = threadIdx.x;
  int lane = t & 63, w = t >> 6;
  int l15 = lane & 15, l4 = lane >> 4;
  __shared__ unsigned short ldsK[4][64 * 64];   // 32 KB ring
  __shared__ unsigned short ldsVT[2][64 * 64];  // 16 KB ring

  const unsigned short* Qp = qws + ((size_t)bh * 2048 + q0 + w * 32) * 64;
  const unsigned short* Kp = kws + (size_t)bh * 2048 * 64;
  const unsigned short* Vp = vws + (size_t)bh * 2048 * 64;

  // Q fragments (B-operand of swapped QK): lane holds Q[q = qs*16+l15][d = kk*32 + l4*8 .. +7]
  bf16x8 aq[2][2];
#pragma unroll
  for (int qs = 0; qs < 2; ++qs)
#pragma unroll
    for (int kk = 0; kk < 2; ++kk)
      aq[qs][kk] = *(const bf16x8*)(Qp + (qs * 16 + l15) * 64 + kk * 32 + l4 * 8);

  f32x4 z = {0.f, 0.f, 0.f, 0.f};
  f32x4 o[2][4];
#pragma unroll
  for (int qs = 0; qs < 2; ++qs)
#pragma unroll
    for (int i = 0; i < 4; ++i) o[qs][i] = z;
  float m_run[2] = {-1e30f, -1e30f};
  float l_run[2] = {0.f, 0.f};

  int kvp = t & 31, d0 = (t >> 5) * 8;
  int osrc[4];
#pragma unroll
  for (int reg = 0; reg < 4; ++reg)
    osrc[reg] = (lane & 48) | (((lane >> 4) & 3) << 2) | reg;

  bf16x8 nvA0, nvA1, nvB0, nvB1;

  // ---- prologue: tiles 0 and 1 ----
  {
    bf16x8 t0a = VLOADR(0, 0), t0b = VLOADR(0, 1);
    nvB0 = VLOADR(64, 0); nvB1 = VLOADR(64, 1);          // V(1) -> set B
    stage_k(Kp, 0, &ldsK[0][0], t);
    stage_k(Kp, 64, &ldsK[1][0], t);
    WAIT_VM0();
    write_vt(&ldsVT[0][0], kvp, d0, t0a, t0b);
    WAIT_LGKM0();
    SBAR();
    __builtin_amdgcn_s_barrier();
    SBAR();
  }

  // ---- main loop: iters 0..27 (7 x 4), then tail 28..31 ----
  for (int mi = 0; mi < 7; ++mi) {
    int base = mi * 4;
    AITER(0, base + 0, true, false);
    AITER(1, base + 1, true, false);
    AITER(2, base + 2, true, false);
    AITER(3, base + 3, true, false);
  }
  AITER(0, 28, true, false);
  AITER(1, 29, true, false);
  AITER(2, 30, false, false);
  AITER(3, 31, false, true);

  // epilogue: normalize and store bf16 [B,S,E].  O row = q = qs*16 + l4*4+reg, col = d = dt*16+l15
  int b = bh >> 4, h = bh & 15;
#pragma unroll
  for (int qs = 0; qs < 2; ++qs) {
    float linv = 1.0f / l_run[qs];
    float oinv[4];
#pragma unroll
    for (int reg = 0; reg < 4; ++reg) oinv[reg] = __shfl(linv, osrc[reg]);
#pragma unroll
    for (int reg = 0; reg < 4; ++reg) {
      int qg = q0 + w * 32 + qs * 16 + l4 * 4 + reg;
#pragma unroll
      for (int dt = 0; dt < 4; ++dt) {
        int d = dt * 16 + l15;
        attnb[((size_t)b * 2048 + qg) * 1024 + h * 64 + d] = f2bf(o[qs][dt][reg] * oinv[reg]);
      }
    }
  }
}

// ---------------- out projection + bias + residual ----------------
__global__ __launch_bounds__(256) void gemm_out(const unsigned short* A, const unsigned short* W,
                                                const float* bias, const float* resid, float* out) {
  __shared__ unsigned short ldsA[128 * 64];
  __shared__ unsigned short ldsB[128 * 64];
  int n0 = blockIdx.x * 128;   // 0..1023
  int m0 = blockIdx.y * 128;
  f32x4 z = {0.f, 0.f, 0.f, 0.f};
  f32x4 acc[4][4];
#pragma unroll
  for (int mm = 0; mm < 4; ++mm)
#pragma unroll
    for (int nn = 0; nn < 4; ++nn) acc[mm][nn] = z;
  gemm_tile(A, W, 1024, m0, n0, ldsA, ldsB, acc);

  int t = threadIdx.x, lane = t & 63, w = t >> 6;
  int wr = w >> 1, wc = w & 1;
  int l15 = lane & 15, l4 = lane >> 4;
#pragma unroll
  for (int mm = 0; mm < 4; ++mm) {
#pragma unroll
    for (int nn = 0; nn < 4; ++nn) {
      int col = n0 + wc * 64 + nn * 16 + l15;
      float bs = bias[col];
#pragma unroll
      for (int reg = 0; reg < 4; ++reg) {
        int r = m0 + wr * 64 + mm * 16 + l4 * 4 + reg;
        size_t off = (size_t)r * 1024 + col;
        out[off] = acc[mm][nn][reg] + bs + resid[off];
      }
    }
  }
}

extern "C" void kernel_launch(void* const* d_in, const int* in_sizes, int n_in,
                              void* d_out, int out_size, void* d_ws, size_t ws_size,
                              hipStream_t stream) {
  const float* in_feats   = (const float*)d_in[0];
  const float* mul_encs   = (const float*)d_in[1];
  const float* add_encs   = (const float*)d_in[2];
  const float* ln_w       = (const float*)d_in[3];
  const float* ln_b       = (const float*)d_in[4];
  const float* in_proj_w  = (const float*)d_in[5];
  const float* in_proj_b  = (const float*)d_in[6];
  const float* out_proj_w = (const float*)d_in[7];
  const float* out_proj_b = (const float*)d_in[8];
  float* out = (float*)d_out;

  unsigned short* ws = (unsigned short*)d_ws;
  unsigned short* values = ws;
  unsigned short* qkin   = values + 4194304;
  unsigned short* wqkv   = qkin + 4194304;
  unsigned short* wout   = wqkv + 3145728;
  unsigned short* qws    = wout + 1048576;
  unsigned short* kws    = qws + 4194304;
  unsigned short* vws    = kws + 4194304;
  unsigned short* attnb  = vws + 4194304;

  wconv<<<4096, 256, 0, stream>>>(in_proj_w, out_proj_w, wqkv, wout);
  preproc<<<4096, 256, 0, stream>>>(in_feats, mul_encs, add_encs, ln_w, ln_b, values, qkin);
  gemm_qkv<<<dim3(24, 32), 256, 0, stream>>>(qkin, values, wqkv, in_proj_b, qws, kws, vws);
  attn_kernel<<<dim3(16, 32), 256, 0, stream>>>(qws, kws, vws, attnb);
  gemm_out<<<dim3(8, 32), 256, 0, stream>>>(attnb, wout, out_proj_b, in_feats, out);
}